// Round 5
// baseline (377.640 us; speedup 1.0000x reference)
//
#include <hip/hip_runtime.h>
#include <hip/hip_bf16.h>

#define E_DIM 128
#define L_DIM 64
#define HDIM 64

__device__ __forceinline__ float waveSum(float v) {
#pragma unroll
  for (int o = 32; o > 0; o >>= 1) v += __shfl_xor(v, o);
  return v;
}
__device__ __forceinline__ float waveMax(float v) {
#pragma unroll
  for (int o = 32; o > 0; o >>= 1) v = fmaxf(v, __shfl_xor(v, o));
  return v;
}

// One wave per (b, k).
// Pass A: lane = neighbor; per-lane row dot with w[E:] (no cross-lane ops),
//         then ONE waveMax + ONE waveSum for the 64-wide softmax.
// Pass B: lane = dim pair (float2); coalesced re-gather, weighted sum.
__global__ __launch_bounds__(256) void phase1(
    const float* __restrict__ user_embs,
    const float* __restrict__ item_embs,
    const float* __restrict__ w_uu,
    const float* __restrict__ w_uiu,
    const float* __restrict__ w_uui,
    const float* __restrict__ W0,
    const float* __restrict__ b0,
    const float* __restrict__ w1,
    const int* __restrict__ uid,
    const int* __restrict__ nbr,
    const int* __restrict__ uiu,
    const int* __restrict__ uui,
    float* __restrict__ feats,     // [3][B][E]
    float* __restrict__ partials,  // [3][B]
    int B) {
  const int lane = threadIdx.x & 63;
  const int wv = threadIdx.x >> 6;  // wave within block (0..3)
  const int w_id = blockIdx.x * 4 + wv;
  const int b = w_id / 3;
  const int k = w_id - 3 * b;
  if (b >= B) return;  // grid is exact for B%4==0; kept for safety

  __shared__ float sc[4][E_DIM];  // per-wave broadcast scratch for inter()

  // ---- per-wave setup (lane = dim pair) ----
  const int u = uid[b];
  const float2 self = *(const float2*)(user_embs + (long)u * E_DIM + lane * 2);

  const float* w = (k == 0) ? w_uu : (k == 1) ? w_uiu : w_uui;
  const float2 wa = *(const float2*)(w + lane * 2);          // w[:E]
  const float2 wb = *(const float2*)(w + E_DIM + lane * 2);  // w[E:]
  const float S1 = waveSum(self.x * wa.x + self.y * wa.y);   // self . w[:E]
  const float S2 = waveSum(self.x * wb.x + self.y * wb.y);   // self . w[E:]

  const bool is_uu = (k == 0);
  const float scale = is_uu ? 0.5f : (1.0f / 3.0f);
  // tables: k==0 -> user; k==1 (uiu) -> item,user; k==2 (uui) -> user,item
  const float* t0 = (k == 1) ? item_embs : user_embs;
  const float* t1 = (k == 1) ? user_embs : item_embs;

  // lane l owns neighbor l's indices (coalesced preload)
  int i0_l, i1_l;
  if (is_uu) {
    i0_l = nbr[b * L_DIM + lane];
    i1_l = 0;
  } else {
    const int* mp = (k == 1) ? uiu : uui;
    i0_l = mp[(b * 2 + 0) * L_DIM + lane];
    i1_l = mp[(b * 2 + 1) * L_DIM + lane];
  }

  // ---- pass A: per-lane row dot(s) against wave-uniform w[E:] ----
  const float4* wE4 = (const float4*)(w + E_DIM);  // uniform -> SGPR operands
  const float4* r0 = (const float4*)(t0 + (long)i0_l * E_DIM);
  const float4* r1 = (const float4*)(t1 + (long)i1_l * E_DIM);
  float d = 0.f;
  if (is_uu) {
#pragma unroll
    for (int c = 0; c < 32; ++c) {
      const float4 v = r0[c];
      const float4 wc = wE4[c];
      d += v.x * wc.x + v.y * wc.y + v.z * wc.z + v.w * wc.w;
    }
  } else {
#pragma unroll
    for (int c = 0; c < 32; ++c) {
      const float4 v0 = r0[c];
      const float4 v1 = r1[c];
      const float4 wc = wE4[c];
      d += (v0.x + v1.x) * wc.x + (v0.y + v1.y) * wc.y +
           (v0.z + v1.z) * wc.z + (v0.w + v1.w) * wc.w;
    }
  }
  float logit = S1 + scale * (S2 + d);
  logit = (logit > 0.f) ? logit : 0.01f * logit;  // leaky_relu
  if (i0_l == 0) logit += -100000000.0f;          // mask

  // 64-wide softmax: exactly two butterflies
  const float M = waveMax(logit);
  const float p = __expf(logit - M);
  const float Z = waveSum(p);
  const float a_l = p / Z;  // lane l holds neighbor l's attention weight

  // ---- pass B: weighted feat sum (lane = dim pair, coalesced) ----
  float o0 = 0.f, o1 = 0.f;
  int i0 = __shfl(i0_l, 0), i1 = __shfl(i1_l, 0);
  float2 g0 = *(const float2*)(t0 + (long)i0 * E_DIM + lane * 2);
  float2 g1 = make_float2(0.f, 0.f);
  if (!is_uu) g1 = *(const float2*)(t1 + (long)i1 * E_DIM + lane * 2);

  for (int l = 0; l < L_DIM; ++l) {
    const float f0 = (self.x + g0.x + g1.x) * scale;
    const float f1 = (self.y + g0.y + g1.y) * scale;
    const float a = __shfl(a_l, l);
    if (l < L_DIM - 1) {  // prefetch next rows
      i0 = __shfl(i0_l, l + 1);
      i1 = __shfl(i1_l, l + 1);
      g0 = *(const float2*)(t0 + (long)i0 * E_DIM + lane * 2);
      if (!is_uu) g1 = *(const float2*)(t1 + (long)i1 * E_DIM + lane * 2);
    }
    o0 += a * f0;
    o1 += a * f1;
  }

  const float r0v = fmaxf(o0, 0.f);
  const float r1v = fmaxf(o1, 0.f);
  *(float2*)(feats + ((long)k * B + b) * E_DIM + lane * 2) =
      make_float2(r0v, r1v);

  // ---- inter(): hid[j] = b0[j] + sum_e r[e] * W0[e][j], j = lane ----
  sc[wv][lane * 2] = r0v;
  sc[wv][lane * 2 + 1] = r1v;
  __syncthreads();  // wave-uniform path; grid exact so all 4 waves arrive

  float hid = b0[lane];
#pragma unroll 4
  for (int e = 0; e < E_DIM; ++e)
    hid += sc[wv][e] * W0[e * HDIM + lane];  // sc: broadcast; W0: L1-hot
  const float pp = tanhf(hid) * w1[lane];
  const float sum = waveSum(pp);
  if (lane == 0) partials[(long)k * B + b] = sum;
}

// One block: sum partials[3][B], softmax over the 3 means -> weights[3].
__global__ __launch_bounds__(256) void reduce_scores(
    const float* __restrict__ partials, float* __restrict__ weights, int B) {
  __shared__ float red[256];
  const int tid = threadIdx.x;
  float s[3];
#pragma unroll
  for (int k = 0; k < 3; ++k) {
    float acc = 0.f;
    for (int i = tid; i < B; i += 256) acc += partials[(long)k * B + i];
    red[tid] = acc;
    __syncthreads();
    for (int off = 128; off > 0; off >>= 1) {
      if (tid < off) red[tid] += red[tid + off];
      __syncthreads();
    }
    s[k] = red[0];
    __syncthreads();
  }
  if (tid == 0) {
    const float inv_b = 1.0f / (float)B;
    const float s0 = s[0] * inv_b, s1 = s[1] * inv_b, s2 = s[2] * inv_b;
    const float m = fmaxf(s0, fmaxf(s1, s2));
    const float e0 = __expf(s0 - m);
    const float e1 = __expf(s1 - m);
    const float e2 = __expf(s2 - m);
    const float inv = 1.0f / (e0 + e1 + e2);
    weights[0] = e0 * inv;
    weights[1] = e1 * inv;
    weights[2] = e2 * inv;
  }
}

__global__ __launch_bounds__(256) void phase2(
    const float* __restrict__ feats, const float* __restrict__ weights,
    float* __restrict__ out, int B) {
  const int i = blockIdx.x * blockDim.x + threadIdx.x;
  const int n = B * E_DIM;
  if (i >= n) return;
  const float w0 = weights[0], w1 = weights[1], w2 = weights[2];
  const float v = w0 * feats[i] + w1 * feats[n + i] + w2 * feats[2 * n + i];
  out[i] = fmaxf(v, 0.f);
}

extern "C" void kernel_launch(void* const* d_in, const int* in_sizes, int n_in,
                              void* d_out, int out_size, void* d_ws,
                              size_t ws_size, hipStream_t stream) {
  const float* user_embs = (const float*)d_in[0];
  const float* item_embs = (const float*)d_in[1];
  const float* w_uu = (const float*)d_in[2];
  const float* w_uiu = (const float*)d_in[3];
  const float* w_uui = (const float*)d_in[4];
  const float* W0 = (const float*)d_in[5];
  const float* b0 = (const float*)d_in[6];
  const float* w1 = (const float*)d_in[7];
  const int* uid = (const int*)d_in[8];
  const int* nbr = (const int*)d_in[9];
  const int* uiu = (const int*)d_in[10];
  const int* uui = (const int*)d_in[11];
  const int B = in_sizes[8];

  float* ws = (float*)d_ws;
  float* partials = ws;            // [3][B]
  float* weights = ws + 3 * B;     // [3]
  float* feats = ws + 3 * B + 64;  // [3][B][E]

  const int n_waves = 3 * B;
  const int n_blocks = (n_waves + 3) / 4;  // 4 waves per 256-thread block
  phase1<<<n_blocks, 256, 0, stream>>>(user_embs, item_embs, w_uu, w_uiu,
                                       w_uui, W0, b0, w1, uid, nbr, uiu, uui,
                                       feats, partials, B);
  reduce_scores<<<1, 256, 0, stream>>>(partials, weights, B);
  const int n = B * E_DIM;
  phase2<<<(n + 255) / 256, 256, 0, stream>>>(feats, weights, (float*)d_out, B);
}

// Round 6
// 235.343 us; speedup vs baseline: 1.6046x; 1.6046x over previous
//
#include <hip/hip_runtime.h>
#include <hip/hip_bf16.h>

#define E_DIM 128
#define L_DIM 64
#define HDIM 64

__device__ __forceinline__ float waveSum(float v) {
#pragma unroll
  for (int o = 32; o > 0; o >>= 1) v += __shfl_xor(v, o);
  return v;
}

__device__ __forceinline__ float bf2f(unsigned int u) {
  return __uint_as_float(u << 16);
}
__device__ __forceinline__ unsigned int f2bf(float f) {  // RNE
  unsigned int u = __float_as_uint(f);
  return (u + 0x7fffu + ((u >> 16) & 1u)) >> 16;
}

// fp32 table -> bf16 table, 4 elems/thread.
__global__ __launch_bounds__(256) void convert_bf16(
    const float* __restrict__ src, unsigned short* __restrict__ dst, int n4) {
  const int i = blockIdx.x * blockDim.x + threadIdx.x;
  if (i >= n4) return;
  const float4 v = ((const float4*)src)[i];
  ushort4 o;
  o.x = (unsigned short)f2bf(v.x);
  o.y = (unsigned short)f2bf(v.y);
  o.z = (unsigned short)f2bf(v.z);
  o.w = (unsigned short)f2bf(v.w);
  ((ushort4*)dst)[i] = o;
}

// One wave per (b, k). Online softmax over 64 neighbors, bf16 tables.
// Lane = embedding dim pair (2*lane, 2*lane+1) packed in one dword.
__global__ __launch_bounds__(256) void phase1_bf16(
    const float* __restrict__ user_embs,   // fp32 (self rows)
    const unsigned short* __restrict__ user_bf,
    const unsigned short* __restrict__ item_bf,
    const float* __restrict__ w_uu,
    const float* __restrict__ w_uiu,
    const float* __restrict__ w_uui,
    const float* __restrict__ W0,
    const float* __restrict__ b0,
    const float* __restrict__ w1,
    const int* __restrict__ uid,
    const int* __restrict__ nbr,
    const int* __restrict__ uiu,
    const int* __restrict__ uui,
    float* __restrict__ feats,     // [3][B][E]
    float* __restrict__ partials,  // [3][B]
    int B) {
  const int lane = threadIdx.x & 63;
  const int wv = threadIdx.x >> 6;
  const int w_id = blockIdx.x * 4 + wv;
  const int b = w_id / 3;
  const int k = w_id - 3 * b;
  if (b >= B) return;

  __shared__ float sc[4][E_DIM];

  const int u = uid[b];
  const float self0 = user_embs[(long)u * E_DIM + lane * 2];
  const float self1 = user_embs[(long)u * E_DIM + lane * 2 + 1];

  const float* w = (k == 0) ? w_uu : (k == 1) ? w_uiu : w_uui;
  const float wa0 = w[lane * 2], wa1 = w[lane * 2 + 1];
  const float wb0 = w[E_DIM + lane * 2], wb1 = w[E_DIM + lane * 2 + 1];
  const float logit_self = waveSum(self0 * wa0 + self1 * wa1);

  const bool is_uu = (k == 0);
  const float scale = is_uu ? 0.5f : (1.0f / 3.0f);
  // tables: k==0 -> user; k==1 (uiu) -> item,user; k==2 (uui) -> user,item
  const unsigned int* t0 =
      (const unsigned int*)((k == 1) ? item_bf : user_bf);
  const unsigned int* t1 =
      (const unsigned int*)((k == 1) ? user_bf : item_bf);

  int i0_l, i1_l;
  if (is_uu) {
    i0_l = nbr[b * L_DIM + lane];
    i1_l = 0;
  } else {
    const int* mp = (k == 1) ? uiu : uui;
    i0_l = mp[(b * 2 + 0) * L_DIM + lane];
    i1_l = mp[(b * 2 + 1) * L_DIM + lane];
  }
  const float mask_l = (i0_l == 0) ? 1.0f : 0.0f;

  // ---- online-softmax stream; rows fetched once, one dword/table/iter ----
  float m = -3.0e38f, s = 0.0f, o0 = 0.0f, o1 = 0.0f;

  int i0 = __shfl(i0_l, 0);
  int i1 = __shfl(i1_l, 0);
  unsigned int p0 = t0[i0 * (E_DIM / 2) + lane];
  unsigned int p1 = 0;
  if (!is_uu) p1 = t1[i1 * (E_DIM / 2) + lane];

  for (int l = 0; l < L_DIM; ++l) {
    const float g00 = bf2f(p0 & 0xffffu), g01 = bf2f(p0 >> 16);
    float g10 = 0.f, g11 = 0.f;
    if (!is_uu) { g10 = bf2f(p1 & 0xffffu); g11 = bf2f(p1 >> 16); }
    const float f0 = (self0 + g00 + g10) * scale;
    const float f1 = (self1 + g01 + g11) * scale;

    if (l < L_DIM - 1) {  // prefetch next row(s)
      i0 = __shfl(i0_l, l + 1);
      i1 = __shfl(i1_l, l + 1);
      p0 = t0[i0 * (E_DIM / 2) + lane];
      if (!is_uu) p1 = t1[i1 * (E_DIM / 2) + lane];
    }

    float logit = waveSum(f0 * wb0 + f1 * wb1) + logit_self;
    logit = (logit > 0.f) ? logit : 0.01f * logit;  // leaky_relu
    logit += -100000000.0f * __shfl(mask_l, l);     // mask

    const float mn = fmaxf(m, logit);
    const float alpha = __expf(m - mn);
    const float p = __expf(logit - mn);
    s = s * alpha + p;
    o0 = o0 * alpha + p * f0;
    o1 = o1 * alpha + p * f1;
    m = mn;
  }

  const float inv_s = 1.0f / s;
  const float r0 = fmaxf(o0 * inv_s, 0.f);
  const float r1 = fmaxf(o1 * inv_s, 0.f);
  *(float2*)(feats + ((long)k * B + b) * E_DIM + lane * 2) =
      make_float2(r0, r1);

  sc[wv][lane * 2] = r0;
  sc[wv][lane * 2 + 1] = r1;
  __syncthreads();

  float hid = b0[lane];
#pragma unroll 4
  for (int e = 0; e < E_DIM; ++e) hid += sc[wv][e] * W0[e * HDIM + lane];
  const float pp = tanhf(hid) * w1[lane];
  const float sum = waveSum(pp);
  if (lane == 0) partials[(long)k * B + b] = sum;
}

// Fallback (proven R4 kernel): fp32 gathers, used only if ws is too small.
__global__ __launch_bounds__(256) void phase1_f32(
    const float* __restrict__ user_embs, const float* __restrict__ item_embs,
    const float* __restrict__ w_uu, const float* __restrict__ w_uiu,
    const float* __restrict__ w_uui, const float* __restrict__ W0,
    const float* __restrict__ b0, const float* __restrict__ w1,
    const int* __restrict__ uid, const int* __restrict__ nbr,
    const int* __restrict__ uiu, const int* __restrict__ uui,
    float* __restrict__ feats, float* __restrict__ partials, int B) {
  const int lane = threadIdx.x & 63;
  const int wv = threadIdx.x >> 6;
  const int w_id = blockIdx.x * 4 + wv;
  const int b = w_id / 3;
  const int k = w_id - 3 * b;
  if (b >= B) return;

  __shared__ float sc[4][E_DIM];
  const int u = uid[b];
  const float self0 = user_embs[u * E_DIM + lane];
  const float self1 = user_embs[u * E_DIM + 64 + lane];
  const float* w = (k == 0) ? w_uu : (k == 1) ? w_uiu : w_uui;
  const float wa0 = w[lane], wa1 = w[64 + lane];
  const float wb0 = w[128 + lane], wb1 = w[192 + lane];
  const float logit_self = waveSum(self0 * wa0 + self1 * wa1);
  const bool is_uu = (k == 0);
  const float scale = is_uu ? 0.5f : (1.0f / 3.0f);
  const float* t0 = (k == 1) ? item_embs : user_embs;
  const float* t1 = (k == 1) ? user_embs : item_embs;
  int i0_l, i1_l;
  if (is_uu) {
    i0_l = nbr[b * L_DIM + lane];
    i1_l = 0;
  } else {
    const int* mp = (k == 1) ? uiu : uui;
    i0_l = mp[(b * 2 + 0) * L_DIM + lane];
    i1_l = mp[(b * 2 + 1) * L_DIM + lane];
  }
  const float mask_l = (i0_l == 0) ? 1.0f : 0.0f;
  float m = -3.0e38f, s = 0.0f, o0 = 0.0f, o1 = 0.0f;
  int i0 = __shfl(i0_l, 0), i1 = __shfl(i1_l, 0);
  float g00 = t0[i0 * E_DIM + lane];
  float g01 = t0[i0 * E_DIM + 64 + lane];
  float g10 = 0.f, g11 = 0.f;
  if (!is_uu) {
    g10 = t1[i1 * E_DIM + lane];
    g11 = t1[i1 * E_DIM + 64 + lane];
  }
  for (int l = 0; l < L_DIM; ++l) {
    const float f0 = (self0 + g00 + g10) * scale;
    const float f1 = (self1 + g01 + g11) * scale;
    if (l < L_DIM - 1) {
      i0 = __shfl(i0_l, l + 1);
      i1 = __shfl(i1_l, l + 1);
      g00 = t0[i0 * E_DIM + lane];
      g01 = t0[i0 * E_DIM + 64 + lane];
      if (!is_uu) {
        g10 = t1[i1 * E_DIM + lane];
        g11 = t1[i1 * E_DIM + 64 + lane];
      }
    }
    float logit = waveSum(f0 * wb0 + f1 * wb1) + logit_self;
    logit = (logit > 0.f) ? logit : 0.01f * logit;
    logit += -100000000.0f * __shfl(mask_l, l);
    const float mn = fmaxf(m, logit);
    const float alpha = __expf(m - mn);
    const float p = __expf(logit - mn);
    s = s * alpha + p;
    o0 = o0 * alpha + p * f0;
    o1 = o1 * alpha + p * f1;
    m = mn;
  }
  const float inv_s = 1.0f / s;
  const float r0 = fmaxf(o0 * inv_s, 0.f);
  const float r1 = fmaxf(o1 * inv_s, 0.f);
  feats[((long)k * B + b) * E_DIM + lane] = r0;
  feats[((long)k * B + b) * E_DIM + 64 + lane] = r1;
  sc[wv][lane] = r0;
  sc[wv][64 + lane] = r1;
  __syncthreads();
  float hid = b0[lane];
#pragma unroll 4
  for (int e = 0; e < E_DIM; ++e) hid += sc[wv][e] * W0[e * HDIM + lane];
  const float p = tanhf(hid) * w1[lane];
  const float sum = waveSum(p);
  if (lane == 0) partials[(long)k * B + b] = sum;
}

__global__ __launch_bounds__(256) void reduce_scores(
    const float* __restrict__ partials, float* __restrict__ weights, int B) {
  __shared__ float red[256];
  const int tid = threadIdx.x;
  float s[3];
#pragma unroll
  for (int k = 0; k < 3; ++k) {
    float acc = 0.f;
    for (int i = tid; i < B; i += 256) acc += partials[(long)k * B + i];
    red[tid] = acc;
    __syncthreads();
    for (int off = 128; off > 0; off >>= 1) {
      if (tid < off) red[tid] += red[tid + off];
      __syncthreads();
    }
    s[k] = red[0];
    __syncthreads();
  }
  if (tid == 0) {
    const float inv_b = 1.0f / (float)B;
    const float s0 = s[0] * inv_b, s1 = s[1] * inv_b, s2 = s[2] * inv_b;
    const float m = fmaxf(s0, fmaxf(s1, s2));
    const float e0 = __expf(s0 - m);
    const float e1 = __expf(s1 - m);
    const float e2 = __expf(s2 - m);
    const float inv = 1.0f / (e0 + e1 + e2);
    weights[0] = e0 * inv;
    weights[1] = e1 * inv;
    weights[2] = e2 * inv;
  }
}

__global__ __launch_bounds__(256) void phase2(
    const float* __restrict__ feats, const float* __restrict__ weights,
    float* __restrict__ out, int B) {
  const int i = blockIdx.x * blockDim.x + threadIdx.x;
  const int n = B * E_DIM;
  if (i >= n) return;
  const float w0 = weights[0], w1 = weights[1], w2 = weights[2];
  const float v = w0 * feats[i] + w1 * feats[n + i] + w2 * feats[2 * n + i];
  out[i] = fmaxf(v, 0.f);
}

extern "C" void kernel_launch(void* const* d_in, const int* in_sizes, int n_in,
                              void* d_out, int out_size, void* d_ws,
                              size_t ws_size, hipStream_t stream) {
  const float* user_embs = (const float*)d_in[0];
  const float* item_embs = (const float*)d_in[1];
  const float* w_uu = (const float*)d_in[2];
  const float* w_uiu = (const float*)d_in[3];
  const float* w_uui = (const float*)d_in[4];
  const float* W0 = (const float*)d_in[5];
  const float* b0 = (const float*)d_in[6];
  const float* w1 = (const float*)d_in[7];
  const int* uid = (const int*)d_in[8];
  const int* nbr = (const int*)d_in[9];
  const int* uiu = (const int*)d_in[10];
  const int* uui = (const int*)d_in[11];
  const int B = in_sizes[8];
  const int nU = in_sizes[0];  // user table elems
  const int nI = in_sizes[1];  // item table elems

  float* ws = (float*)d_ws;
  float* partials = ws;            // [3][B]
  float* weights = ws + 3 * B;     // [3] (+pad to 64)
  float* feats = ws + 3 * B + 64;  // [3][B][E]
  const size_t f32_floats = (size_t)3 * B + 64 + (size_t)3 * B * E_DIM;
  unsigned short* user_bf = (unsigned short*)(ws + f32_floats);
  unsigned short* item_bf = user_bf + nU;
  const size_t need = f32_floats * 4 + ((size_t)nU + nI) * 2;

  const int n_waves = 3 * B;
  const int n_blocks = (n_waves + 3) / 4;

  if (ws_size >= need) {
    convert_bf16<<<(nU / 4 + 255) / 256, 256, 0, stream>>>(user_embs, user_bf,
                                                           nU / 4);
    convert_bf16<<<(nI / 4 + 255) / 256, 256, 0, stream>>>(item_embs, item_bf,
                                                           nI / 4);
    phase1_bf16<<<n_blocks, 256, 0, stream>>>(
        user_embs, user_bf, item_bf, w_uu, w_uiu, w_uui, W0, b0, w1, uid, nbr,
        uiu, uui, feats, partials, B);
  } else {
    phase1_f32<<<n_blocks, 256, 0, stream>>>(user_embs, item_embs, w_uu,
                                             w_uiu, w_uui, W0, b0, w1, uid,
                                             nbr, uiu, uui, feats, partials, B);
  }
  reduce_scores<<<1, 256, 0, stream>>>(partials, weights, B);
  const int n = B * E_DIM;
  phase2<<<(n + 255) / 256, 256, 0, stream>>>(feats, weights, (float*)d_out, B);
}